// Round 9
// baseline (110.848 us; speedup 1.0000x reference)
//
#include <hip/hip_runtime.h>
#include <hip/hip_bf16.h>

typedef __attribute__((ext_vector_type(8))) short short8;      // 8 x bf16
typedef __attribute__((ext_vector_type(16))) float f32x16;     // 32x32 MFMA C/D
typedef __attribute__((ext_vector_type(4))) unsigned int uint4v;

#define NB 2
#define NS 2048
#define NH 16
#define ND 128
#define ROWS (NH * ND)       // 2048 floats between consecutive seq positions
#define KVBLK 64
#define QBLK 256             // 8 waves x 32 q-rows
#define NTILE (NS / KVBLK)   // 32
#define NQB (NS / QBLK)      // 8
#define NWIN (NTILE / 2)     // 16 windows of 2 KV tiles
#define TILEB 16384          // one staged K or V tile image = 64 rows x 256B

__device__ __forceinline__ unsigned short f2bf(float f) {
  union { __hip_bfloat16 b; unsigned short u; } c;
  c.b = __float2bfloat16(f);  // RNE
  return c.u;
}

__device__ __forceinline__ short8 pack8(float4 a, float4 b, float s) {
  short8 r;
  r[0] = (short)f2bf(a.x * s); r[1] = (short)f2bf(a.y * s);
  r[2] = (short)f2bf(a.z * s); r[3] = (short)f2bf(a.w * s);
  r[4] = (short)f2bf(b.x * s); r[5] = (short)f2bf(b.y * s);
  r[6] = (short)f2bf(b.z * s); r[7] = (short)f2bf(b.w * s);
  return r;
}

__device__ __forceinline__ void dma16(const void* g, void* l) {
  __builtin_amdgcn_global_load_lds(
      (const __attribute__((address_space(1))) unsigned int*)g,
      (__attribute__((address_space(3))) unsigned int*)l, 16, 0, 0);
}

__device__ __forceinline__ void pl32swap(unsigned int& a, unsigned int& b) {
  asm("v_permlane32_swap_b32 %0, %1" : "+v"(a), "+v"(b));
}

// ---------------- prepass -> per-tile PRE-SWIZZLED linear images (as R8) ---------
// K image: row r, 16B-chunk c at slot (c ^ (r&15)). V image: row r = d-pair
// (2r,2r+1); chunk j<8 -> d=2r,k=j*8..; j>=8 -> d=2r+1,k=(j-8)*8..; slot j^(r&15).
__global__ __launch_bounds__(256) void prepass_kv(
    const float* __restrict__ Kg, const float* __restrict__ Vg,
    char* __restrict__ Kbt, char* __restrict__ Vbt) {
  const int blk = blockIdx.x;          // bh*NTILE + t
  const int t = blk & (NTILE - 1);
  const int bh = blk >> 5;
  const int h = bh & (NH - 1);
  const int b = bh >> 4;
  const int tid = threadIdx.x;

  const size_t ibase = (size_t)b * NS * ROWS + (size_t)h * ND + (size_t)t * KVBLK * ROWS;
  const float* Kp = Kg + ibase;
  const float* Vp = Vg + ibase;
  char* Kt = Kbt + (size_t)blk * TILEB;
  char* Vt = Vbt + (size_t)blk * TILEB;

#pragma unroll
  for (int j = 0; j < 4; ++j) {
    const int r = j * 16 + (tid >> 4);
    const int c = tid & 15;
    const float* src = Kp + (size_t)r * ROWS + c * 8;
    float4 a = *reinterpret_cast<const float4*>(src);
    float4 d = *reinterpret_cast<const float4*>(src + 4);
    *reinterpret_cast<short8*>(Kt + r * 256 + (((c ^ (r & 15)) << 4))) = pack8(a, d, 1.0f);
  }

  __shared__ float vt[64][129];
#pragma unroll
  for (int j = 0; j < 4; ++j) {
    const int r = j * 16 + (tid >> 4);
    const int c0 = (tid & 15) * 8;
    float4 a = *reinterpret_cast<const float4*>(Vp + (size_t)r * ROWS + c0);
    float4 d = *reinterpret_cast<const float4*>(Vp + (size_t)r * ROWS + c0 + 4);
    vt[r][c0 + 0] = a.x; vt[r][c0 + 1] = a.y; vt[r][c0 + 2] = a.z; vt[r][c0 + 3] = a.w;
    vt[r][c0 + 4] = d.x; vt[r][c0 + 5] = d.y; vt[r][c0 + 6] = d.z; vt[r][c0 + 7] = d.w;
  }
  __syncthreads();
#pragma unroll
  for (int it = 0; it < 4; ++it) {
    const int item = it * 256 + tid;
    const int r = item >> 4;
    const int j = item & 15;
    const int d = 2 * r + (j >> 3);
    const int k0 = (j & 7) * 8;
    short8 o8;
#pragma unroll
    for (int i = 0; i < 8; ++i) o8[i] = (short)f2bf(vt[k0 + i][d]);
    *reinterpret_cast<short8*>(Vt + r * 256 + (((j ^ (r & 15)) << 4))) = o8;
  }
}

// ---------------- main: 8-wave block, 2-tile windows, 4-slot LDS pipeline --------
// S^T = mfma(A=K, B=Q); O^T = mfma(A=V^T, B=P^T), P^T in-register (permlane32_swap).
// No-max softmax; log2e folded into Q scale. Per window: stage 2 tiles (8 DMA/thr)
// into the free slot-pair, compute QK for BOTH tiles (4 independent MFMA chains),
// then softmax+PV per tile. LDS offsets loop-invariant (qkoff/pvoff), mt/dt
// variants are compile-time immediates. One vmcnt(0)+barrier per window.
__global__ __launch_bounds__(512, 2) void fattn_fwd(
    const float* __restrict__ Qg, const char* __restrict__ Kbt,
    const char* __restrict__ Vbt, float* __restrict__ Og) {
  // 4 tile-slots x (K 16KB | V 16KB) = 128 KB
  __shared__ __align__(16) char lds[131072];
  const int tid = threadIdx.x;
  const int l = tid & 63;
  const int w = tid >> 6;          // 0..7
  const int l31 = l & 31;
  const int hi2 = l >> 5;

  // XCD swizzle (nwg=256, %8==0): 32 consecutive wg per XCD = 4 full bh groups.
  const int orig = blockIdx.x;
  const int wg = (orig & 7) * 32 + (orig >> 3);
  const int qblk = wg & (NQB - 1);
  const int bh = wg >> 3;
  const int h = bh & (NH - 1);
  const int b = bh >> 4;

  const float* Qp = Qg + (size_t)b * NS * ROWS + (size_t)h * ND;
  float* Op = Og + (size_t)b * NS * ROWS + (size_t)h * ND;
  const char* Ktiles = Kbt + (size_t)bh * NTILE * TILEB;
  const char* Vtiles = Vbt + (size_t)bh * NTILE * TILEB;

  const float scale = 0.08838834764831845f * 1.4426950408889634f;  // 1/sqrt(D)*log2e

  // ---- Q frags (held in regs): q-row = lane&31, k(d) = hi2*8 + e + 16*ks ----
  const int qrow = qblk * QBLK + w * 32 + l31;
  short8 qf[8];
  {
    const float* qr = Qp + (size_t)qrow * ROWS + hi2 * 8;
#pragma unroll
    for (int ks = 0; ks < 8; ++ks) {
      float4 a = *reinterpret_cast<const float4*>(qr + ks * 16);
      float4 c = *reinterpret_cast<const float4*>(qr + ks * 16 + 4);
      qf[ks] = pack8(a, c, scale);
    }
  }

  // ---- loop-invariant LDS byte offsets (2-way-max bank aliasing by image swz) ----
  int qkoff[8], pvoff[4];
  {
    const int rsw = (l31 & 15) << 4;
#pragma unroll
    for (int ks = 0; ks < 8; ++ks)
      qkoff[ks] = l31 * 256 + ((ks * 32 + hi2 * 16) ^ rsw);   // mt1: +8192
    const int vsw = ((l31 >> 1) & 15) << 4;
#pragma unroll
    for (int ks = 0; ks < 4; ++ks)
      pvoff[ks] = (l31 >> 1) * 256 +
                  ((((l31 & 1) * 128) + ks * 32 + hi2 * 16) ^ vsw);  // dt: +dt*4096
  }

  // stage one tile image (K 16KB + V 16KB) into slot s: 4 dma16 per thread
  auto stageT = [&](int t, int s) {
    const char* Ks = Ktiles + (size_t)t * TILEB;
    const char* Vs = Vtiles + (size_t)t * TILEB;
    char* kd = lds + s * 32768;
    char* vd = kd + 16384;
#pragma unroll
    for (int i = 0; i < 2; ++i) {
      const int off = i * 8192 + w * 1024;        // wave-uniform LDS base
      dma16(Ks + off + l * 16, kd + off);
      dma16(Vs + off + l * 16, vd + off);
    }
  };

  f32x16 o[4];
#pragma unroll
  for (int dt = 0; dt < 4; ++dt) o[dt] = 0.f;
  float l_acc = 0.f;

  // softmax+pack one mt accumulator -> 2 P^T B-frags
  auto smpack = [&](const f32x16& acc, short8* out2) {
    f32x16 p;
#pragma unroll
    for (int r = 0; r < 16; ++r) p[r] = exp2f(acc[r]);
    float s = 0.f;
#pragma unroll
    for (int r = 0; r < 16; ++r) s += p[r];
    l_acc += s;
#pragma unroll
    for (int half = 0; half < 2; ++half) {
      unsigned int X[4];
#pragma unroll
      for (int j = 0; j < 4; ++j)
        X[j] = (unsigned int)f2bf(p[half * 8 + 2 * j]) |
               ((unsigned int)f2bf(p[half * 8 + 2 * j + 1]) << 16);
      pl32swap(X[0], X[2]);
      pl32swap(X[1], X[3]);
      uint4v u = {X[0], X[1], X[2], X[3]};
      out2[half] = __builtin_bit_cast(short8, u);
    }
  };

  // PV for one tile from V base vb
  auto pv = [&](const char* vb, const short8* pf) {
    __builtin_amdgcn_s_setprio(1);
#pragma unroll
    for (int dt = 0; dt < 4; ++dt) {
#pragma unroll
      for (int ks = 0; ks < 4; ++ks) {
        short8 vf = *reinterpret_cast<const short8*>(vb + pvoff[ks] + dt * 4096);
        o[dt] = __builtin_amdgcn_mfma_f32_32x32x16_bf16(vf, pf[ks], o[dt], 0, 0, 0);
      }
    }
    __builtin_amdgcn_s_setprio(0);
  };

  // ---- prologue: stage tiles 0,1 into slots 0,1 ----
  stageT(0, 0);
  stageT(1, 1);
  asm volatile("s_waitcnt vmcnt(0)" ::: "memory");
  __syncthreads();

#pragma unroll 1
  for (int j = 0; j < NWIN; ++j) {
    // stage next window's pair into the free slot-pair
    if (j + 1 < NWIN) {
      const int s0 = ((j & 1) ^ 1) * 2;
      stageT(2 * j + 2, s0);
      stageT(2 * j + 3, s0 + 1);
    }
    const char* kb0 = lds + (j & 1) * 65536;
    const char* kb1 = kb0 + 32768;

    // ---- QK both tiles: 4 independent accumulator chains, 32 MFMA ----
    f32x16 a00 = 0.f, a01 = 0.f, a10 = 0.f, a11 = 0.f;
    __builtin_amdgcn_s_setprio(1);
#pragma unroll
    for (int ks = 0; ks < 8; ++ks) {
      short8 k0 = *reinterpret_cast<const short8*>(kb0 + qkoff[ks]);
      a00 = __builtin_amdgcn_mfma_f32_32x32x16_bf16(k0, qf[ks], a00, 0, 0, 0);
      short8 k1 = *reinterpret_cast<const short8*>(kb0 + qkoff[ks] + 8192);
      a01 = __builtin_amdgcn_mfma_f32_32x32x16_bf16(k1, qf[ks], a01, 0, 0, 0);
      short8 k2 = *reinterpret_cast<const short8*>(kb1 + qkoff[ks]);
      a10 = __builtin_amdgcn_mfma_f32_32x32x16_bf16(k2, qf[ks], a10, 0, 0, 0);
      short8 k3 = *reinterpret_cast<const short8*>(kb1 + qkoff[ks] + 8192);
      a11 = __builtin_amdgcn_mfma_f32_32x32x16_bf16(k3, qf[ks], a11, 0, 0, 0);
    }
    __builtin_amdgcn_s_setprio(0);

    // ---- tile 0: softmax+pack, PV ----
    short8 pf[4];
    smpack(a00, pf + 0);
    smpack(a01, pf + 2);
    pv(kb0 + 16384, pf);
    // ---- tile 1 ----
    smpack(a10, pf + 0);
    smpack(a11, pf + 2);
    pv(kb1 + 16384, pf);

    if (j + 1 < NWIN) {
      asm volatile("s_waitcnt vmcnt(0)" ::: "memory");
      __syncthreads();
    }
  }

  // ---- epilogue: l = own + cross-half; normalize + store ----
  const float lt = l_acc + __shfl_xor(l_acc, 32);
  const float inv = 1.0f / lt;
  float* orow = Op + (size_t)qrow * ROWS;
#pragma unroll
  for (int dt = 0; dt < 4; ++dt) {
#pragma unroll
    for (int g = 0; g < 4; ++g) {
      float4 v;
      v.x = o[dt][g * 4 + 0] * inv;
      v.y = o[dt][g * 4 + 1] * inv;
      v.z = o[dt][g * 4 + 2] * inv;
      v.w = o[dt][g * 4 + 3] * inv;
      *reinterpret_cast<float4*>(orow + dt * 32 + g * 8 + hi2 * 4) = v;
    }
  }
}

extern "C" void kernel_launch(void* const* d_in, const int* in_sizes, int n_in,
                              void* d_out, int out_size, void* d_ws, size_t ws_size,
                              hipStream_t stream) {
  const float* q = (const float*)d_in[0];
  const float* k = (const float*)d_in[1];
  const float* v = (const float*)d_in[2];
  float* out = (float*)d_out;
  (void)in_sizes; (void)n_in; (void)out_size; (void)ws_size;
  char* Kbt = (char*)d_ws;                                  // 32bh*32t*16KB = 16.8MB
  char* Vbt = Kbt + (size_t)NB * NH * NTILE * TILEB;        // 16.8MB
  prepass_kv<<<dim3(NB * NH * NTILE), dim3(256), 0, stream>>>(k, v, Kbt, Vbt);
  fattn_fwd<<<dim3(NQB * NB * NH), dim3(512), 0, stream>>>(q, Kbt, Vbt, out);
}

// Round 10
// 108.231 us; speedup vs baseline: 1.0242x; 1.0242x over previous
//
#include <hip/hip_runtime.h>
#include <hip/hip_bf16.h>

typedef __attribute__((ext_vector_type(8))) short short8;      // 8 x bf16
typedef __attribute__((ext_vector_type(16))) float f32x16;     // 32x32 MFMA C/D
typedef __attribute__((ext_vector_type(4))) unsigned int uint4v;

#define NB 2
#define NS 2048
#define NH 16
#define ND 128
#define ROWS (NH * ND)       // 2048 floats between consecutive seq positions
#define KVBLK 64
#define QBLK 256             // 8 waves x 32 q-rows
#define NTILE (NS / KVBLK)   // 32
#define NQB (NS / QBLK)      // 8
#define NWIN (NTILE / 2)     // 16 windows of 2 KV tiles
#define TILEB 16384          // one staged K or V tile image = 64 rows x 256B

__device__ __forceinline__ unsigned short f2bf(float f) {
  union { __hip_bfloat16 b; unsigned short u; } c;
  c.b = __float2bfloat16(f);  // RNE
  return c.u;
}

__device__ __forceinline__ short8 pack8(float4 a, float4 b, float s) {
  short8 r;
  r[0] = (short)f2bf(a.x * s); r[1] = (short)f2bf(a.y * s);
  r[2] = (short)f2bf(a.z * s); r[3] = (short)f2bf(a.w * s);
  r[4] = (short)f2bf(b.x * s); r[5] = (short)f2bf(b.y * s);
  r[6] = (short)f2bf(b.z * s); r[7] = (short)f2bf(b.w * s);
  return r;
}

__device__ __forceinline__ void dma16(const void* g, void* l) {
  __builtin_amdgcn_global_load_lds(
      (const __attribute__((address_space(1))) unsigned int*)g,
      (__attribute__((address_space(3))) unsigned int*)l, 16, 0, 0);
}

__device__ __forceinline__ void pl32swap(unsigned int& a, unsigned int& b) {
  asm("v_permlane32_swap_b32 %0, %1" : "+v"(a), "+v"(b));
}

// ---------------- prepass -> per-tile PRE-SWIZZLED linear images (as R8/R9) ------
// K image: row r, 16B-chunk c at slot (c ^ (r&15)). V image: row r = d-pair
// (2r,2r+1); chunk j<8 -> d=2r,k=j*8..; j>=8 -> d=2r+1,k=(j-8)*8..; slot j^(r&15).
__global__ __launch_bounds__(256) void prepass_kv(
    const float* __restrict__ Kg, const float* __restrict__ Vg,
    char* __restrict__ Kbt, char* __restrict__ Vbt) {
  const int blk = blockIdx.x;          // bh*NTILE + t
  const int t = blk & (NTILE - 1);
  const int bh = blk >> 5;
  const int h = bh & (NH - 1);
  const int b = bh >> 4;
  const int tid = threadIdx.x;

  const size_t ibase = (size_t)b * NS * ROWS + (size_t)h * ND + (size_t)t * KVBLK * ROWS;
  const float* Kp = Kg + ibase;
  const float* Vp = Vg + ibase;
  char* Kt = Kbt + (size_t)blk * TILEB;
  char* Vt = Vbt + (size_t)blk * TILEB;

#pragma unroll
  for (int j = 0; j < 4; ++j) {
    const int r = j * 16 + (tid >> 4);
    const int c = tid & 15;
    const float* src = Kp + (size_t)r * ROWS + c * 8;
    float4 a = *reinterpret_cast<const float4*>(src);
    float4 d = *reinterpret_cast<const float4*>(src + 4);
    *reinterpret_cast<short8*>(Kt + r * 256 + (((c ^ (r & 15)) << 4))) = pack8(a, d, 1.0f);
  }

  __shared__ float vt[64][129];
#pragma unroll
  for (int j = 0; j < 4; ++j) {
    const int r = j * 16 + (tid >> 4);
    const int c0 = (tid & 15) * 8;
    float4 a = *reinterpret_cast<const float4*>(Vp + (size_t)r * ROWS + c0);
    float4 d = *reinterpret_cast<const float4*>(Vp + (size_t)r * ROWS + c0 + 4);
    vt[r][c0 + 0] = a.x; vt[r][c0 + 1] = a.y; vt[r][c0 + 2] = a.z; vt[r][c0 + 3] = a.w;
    vt[r][c0 + 4] = d.x; vt[r][c0 + 5] = d.y; vt[r][c0 + 6] = d.z; vt[r][c0 + 7] = d.w;
  }
  __syncthreads();
#pragma unroll
  for (int it = 0; it < 4; ++it) {
    const int item = it * 256 + tid;
    const int r = item >> 4;
    const int j = item & 15;
    const int d = 2 * r + (j >> 3);
    const int k0 = (j & 7) * 8;
    short8 o8;
#pragma unroll
    for (int i = 0; i < 8; ++i) o8[i] = (short)f2bf(vt[k0 + i][d]);
    *reinterpret_cast<short8*>(Vt + r * 256 + (((j ^ (r & 15)) << 4))) = o8;
  }
}

// ---------------- main: 8-wave block, 2-tile windows, UNFENCED interleave --------
// No s_setprio anywhere in the loop (it is a scheduling fence: VALU could never
// enter MFMA shadows). Window body ordered so each softmax slab sits next to an
// MFMA cluster it does NOT feed: QK(t0) -> QK(t1)||SM(t0) -> PV(t0)||SM(t1) ->
// PV(t1). PV is split per-mt (pf pairs), all state in named registers.
__global__ __launch_bounds__(512, 2) void fattn_fwd(
    const float* __restrict__ Qg, const char* __restrict__ Kbt,
    const char* __restrict__ Vbt, float* __restrict__ Og) {
  // 4 tile-slots x (K 16KB | V 16KB) = 128 KB
  __shared__ __align__(16) char lds[131072];
  const int tid = threadIdx.x;
  const int l = tid & 63;
  const int w = tid >> 6;          // 0..7
  const int l31 = l & 31;
  const int hi2 = l >> 5;

  // XCD swizzle (nwg=256, %8==0): 32 consecutive wg per XCD = 4 full bh groups.
  const int orig = blockIdx.x;
  const int wg = (orig & 7) * 32 + (orig >> 3);
  const int qblk = wg & (NQB - 1);
  const int bh = wg >> 3;
  const int h = bh & (NH - 1);
  const int b = bh >> 4;

  const float* Qp = Qg + (size_t)b * NS * ROWS + (size_t)h * ND;
  float* Op = Og + (size_t)b * NS * ROWS + (size_t)h * ND;
  const char* Ktiles = Kbt + (size_t)bh * NTILE * TILEB;
  const char* Vtiles = Vbt + (size_t)bh * NTILE * TILEB;

  const float scale = 0.08838834764831845f * 1.4426950408889634f;  // 1/sqrt(D)*log2e

  // ---- Q frags in regs ----
  const int qrow = qblk * QBLK + w * 32 + l31;
  short8 qf[8];
  {
    const float* qr = Qp + (size_t)qrow * ROWS + hi2 * 8;
#pragma unroll
    for (int ks = 0; ks < 8; ++ks) {
      float4 a = *reinterpret_cast<const float4*>(qr + ks * 16);
      float4 c = *reinterpret_cast<const float4*>(qr + ks * 16 + 4);
      qf[ks] = pack8(a, c, scale);
    }
  }

  // ---- loop-invariant LDS byte offsets (2-way-max aliasing via image swizzle) ----
  int qkoff[8], pvoff[4];
  {
    const int rsw = (l31 & 15) << 4;
#pragma unroll
    for (int ks = 0; ks < 8; ++ks)
      qkoff[ks] = l31 * 256 + ((ks * 32 + hi2 * 16) ^ rsw);   // mt1: +8192
    const int vsw = ((l31 >> 1) & 15) << 4;
#pragma unroll
    for (int ks = 0; ks < 4; ++ks)
      pvoff[ks] = (l31 >> 1) * 256 +
                  ((((l31 & 1) * 128) + ks * 32 + hi2 * 16) ^ vsw);  // dt: +dt*4096
  }

  auto stageT = [&](int t, int s) {
    const char* Ks = Ktiles + (size_t)t * TILEB;
    const char* Vs = Vtiles + (size_t)t * TILEB;
    char* kd = lds + s * 32768;
    char* vd = kd + 16384;
#pragma unroll
    for (int i = 0; i < 2; ++i) {
      const int off = i * 8192 + w * 1024;        // wave-uniform LDS base
      dma16(Ks + off + l * 16, kd + off);
      dma16(Vs + off + l * 16, vd + off);
    }
  };

  f32x16 o[4];
#pragma unroll
  for (int dt = 0; dt < 4; ++dt) o[dt] = 0.f;
  float l_acc = 0.f;

  // 8-step QK chain over one 32-row K half (base kb: +0 for mt0, +8192 for mt1)
  auto qkc = [&](const char* kb) -> f32x16 {
    f32x16 a = 0.f;
#pragma unroll
    for (int ks = 0; ks < 8; ++ks) {
      short8 kf = *reinterpret_cast<const short8*>(kb + qkoff[ks]);
      a = __builtin_amdgcn_mfma_f32_32x32x16_bf16(kf, qf[ks], a, 0, 0, 0);
    }
    return a;
  };

  // softmax one half-accumulator -> 2 P^T B-frags (+ l via balanced tree)
  auto sm = [&](const f32x16& acc, short8& f0, short8& f1) {
    f32x16 p;
#pragma unroll
    for (int r = 0; r < 16; ++r) p[r] = exp2f(acc[r]);
    float s01 = (p[0] + p[1]) + (p[2] + p[3]);
    float s23 = (p[4] + p[5]) + (p[6] + p[7]);
    float s45 = (p[8] + p[9]) + (p[10] + p[11]);
    float s67 = (p[12] + p[13]) + (p[14] + p[15]);
    l_acc += (s01 + s23) + (s45 + s67);
    unsigned int X[4];
#pragma unroll
    for (int j = 0; j < 4; ++j)
      X[j] = (unsigned int)f2bf(p[2 * j]) | ((unsigned int)f2bf(p[2 * j + 1]) << 16);
    pl32swap(X[0], X[2]);
    pl32swap(X[1], X[3]);
    uint4v u0 = {X[0], X[1], X[2], X[3]};
    f0 = __builtin_bit_cast(short8, u0);
    unsigned int Y[4];
#pragma unroll
    for (int j = 0; j < 4; ++j)
      Y[j] = (unsigned int)f2bf(p[8 + 2 * j]) | ((unsigned int)f2bf(p[8 + 2 * j + 1]) << 16);
    pl32swap(Y[0], Y[2]);
    pl32swap(Y[1], Y[3]);
    uint4v u1 = {Y[0], Y[1], Y[2], Y[3]};
    f1 = __builtin_bit_cast(short8, u1);
  };

  // PV half-tile: ks slots {ks0, ks0+1} with frags f0,f1 (ks0 is a literal)
  auto pvh = [&](const char* vb, int ks0, short8 f0, short8 f1) {
#pragma unroll
    for (int dt = 0; dt < 4; ++dt) {
      short8 v0 = *reinterpret_cast<const short8*>(vb + pvoff[ks0] + dt * 4096);
      o[dt] = __builtin_amdgcn_mfma_f32_32x32x16_bf16(v0, f0, o[dt], 0, 0, 0);
      short8 v1 = *reinterpret_cast<const short8*>(vb + pvoff[ks0 + 1] + dt * 4096);
      o[dt] = __builtin_amdgcn_mfma_f32_32x32x16_bf16(v1, f1, o[dt], 0, 0, 0);
    }
  };

  // ---- prologue: stage tiles 0,1 into slots 0,1 ----
  stageT(0, 0);
  stageT(1, 1);
  asm volatile("s_waitcnt vmcnt(0)" ::: "memory");
  __syncthreads();

#pragma unroll 1
  for (int j = 0; j < NWIN; ++j) {
    if (j + 1 < NWIN) {
      const int s0 = ((j & 1) ^ 1) * 2;
      stageT(2 * j + 2, s0);
      stageT(2 * j + 3, s0 + 1);
    }
    const char* kb0 = lds + (j & 1) * 65536;
    const char* kb1 = kb0 + 32768;
    const char* vb0 = kb0 + 16384;
    const char* vb1 = kb1 + 16384;

    // cluster 1: QK(tile0) — 16 MFMA
    f32x16 a0 = qkc(kb0);
    f32x16 a1 = qkc(kb0 + 8192);
    // cluster 2: QK(tile1) — 16 MFMA; SM(tile0) VALU is dep-free against it
    f32x16 a2 = qkc(kb1);
    f32x16 a3 = qkc(kb1 + 8192);
    short8 p00, p01, p10, p11;
    sm(a0, p00, p01);
    sm(a1, p10, p11);
    // cluster 3: PV(tile0) — 16 MFMA; SM(tile1) VALU dep-free against it
    pvh(vb0, 0, p00, p01);
    pvh(vb0, 2, p10, p11);
    short8 p20, p21, p30, p31;
    sm(a2, p20, p21);
    sm(a3, p30, p31);
    // cluster 4: PV(tile1) — 16 MFMA
    pvh(vb1, 0, p20, p21);
    pvh(vb1, 2, p30, p31);

    if (j + 1 < NWIN) {
      asm volatile("s_waitcnt vmcnt(0)" ::: "memory");
      __syncthreads();
    }
  }

  // ---- epilogue: l = own + cross-half; normalize + store ----
  const float lt = l_acc + __shfl_xor(l_acc, 32);
  const float inv = 1.0f / lt;
  float* orow = Op + (size_t)qrow * ROWS;
#pragma unroll
  for (int dt = 0; dt < 4; ++dt) {
#pragma unroll
    for (int g = 0; g < 4; ++g) {
      float4 v;
      v.x = o[dt][g * 4 + 0] * inv;
      v.y = o[dt][g * 4 + 1] * inv;
      v.z = o[dt][g * 4 + 2] * inv;
      v.w = o[dt][g * 4 + 3] * inv;
      *reinterpret_cast<float4*>(orow + dt * 32 + g * 8 + hi2 * 4) = v;
    }
  }
}

extern "C" void kernel_launch(void* const* d_in, const int* in_sizes, int n_in,
                              void* d_out, int out_size, void* d_ws, size_t ws_size,
                              hipStream_t stream) {
  const float* q = (const float*)d_in[0];
  const float* k = (const float*)d_in[1];
  const float* v = (const float*)d_in[2];
  float* out = (float*)d_out;
  (void)in_sizes; (void)n_in; (void)out_size; (void)ws_size;
  char* Kbt = (char*)d_ws;                                  // 32bh*32t*16KB = 16.8MB
  char* Vbt = Kbt + (size_t)NB * NH * NTILE * TILEB;        // 16.8MB
  prepass_kv<<<dim3(NB * NH * NTILE), dim3(256), 0, stream>>>(k, v, Kbt, Vbt);
  fattn_fwd<<<dim3(NQB * NB * NH), dim3(512), 0, stream>>>(q, Kbt, Vbt, out);
}